// Round 1
// baseline (97.041 us; speedup 1.0000x reference)
//
#include <hip/hip_runtime.h>

#define KK      3
#define CIN     32
#define OCH     64
#define HH      56
#define WW      56
#define BB      4
#define OT      4              // output channels per block
#define TH      4              // output rows per block
#define CG      8              // channels staged per LDS phase
#define HALO_H  (TH + 2)       // 6
#define HALO_W  (WW + 2)       // 58
#define CH_STRIDE (HALO_H * HALO_W)   // 348 floats per channel
#define NW      18432          // 64*32*3*3 weight elements

__global__ __launch_bounds__(256) void absmean_reduce(const float* __restrict__ w,
                                                      float* __restrict__ ws) {
    int idx = (blockIdx.x * 256 + threadIdx.x) * 4;   // 18 blocks * 256 * 4 = 18432
    float4 v = *reinterpret_cast<const float4*>(w + idx);
    float s = fabsf(v.x) + fabsf(v.y) + fabsf(v.z) + fabsf(v.w);
    #pragma unroll
    for (int off = 32; off > 0; off >>= 1)
        s += __shfl_down(s, off);
    __shared__ float smem[4];
    int lane = threadIdx.x & 63, wv = threadIdx.x >> 6;
    if (lane == 0) smem[wv] = s;
    __syncthreads();
    if (threadIdx.x == 0)
        atomicAdd(ws, smem[0] + smem[1] + smem[2] + smem[3]);
}

__global__ __launch_bounds__(256) void minconv_kernel(const float* __restrict__ x,
                                                      const float* __restrict__ wts,
                                                      const float* __restrict__ ws,
                                                      float* __restrict__ out) {
    __shared__ float xs[CG * CH_STRIDE];   // 8*6*58*4B = 11136 B

    const int ht  = blockIdx.x;        // 0..13
    const int ot  = blockIdx.y;        // 0..15
    const int b   = blockIdx.z;        // 0..3
    const int h0  = ht * TH;
    const int o0  = ot * OT;
    const int tid = threadIdx.x;

    const int pix    = tid;            // pixel within 56x4 tile
    const int pw     = pix % WW;
    const int ph     = pix / WW;
    const bool active = (pix < TH * WW);   // 224 of 256

    float acc[OT] = {0.f, 0.f, 0.f, 0.f};
    const float* wbase = wts + o0 * (CIN * 9);

    for (int cg = 0; cg < CIN; cg += CG) {
        __syncthreads();   // protect previous phase's LDS reads
        // stage CG channels: rows h0-1..h0+TH, cols -1..WW (zero padded)
        for (int i = tid; i < CG * CH_STRIDE; i += 256) {
            int c  = i / CH_STRIDE;
            int r  = (i / HALO_W) % HALO_H;
            int cc = i % HALO_W;
            int gh = h0 - 1 + r;
            int gw = cc - 1;
            float v = 0.f;
            if (gh >= 0 && gh < HH && gw >= 0 && gw < WW)
                v = x[((b * CIN + cg + c) * HH + gh) * WW + gw];
            xs[i] = v;
        }
        __syncthreads();

        if (active) {
            for (int c = 0; c < CG; ++c) {
                const float* xp = xs + c * CH_STRIDE + ph * HALO_W + pw;
                float xv[9];
                #pragma unroll
                for (int kh = 0; kh < 3; ++kh)
                    #pragma unroll
                    for (int kw = 0; kw < 3; ++kw)
                        xv[kh * 3 + kw] = xp[kh * HALO_W + kw];
                const float* wp = wbase + (cg + c) * 9;   // uniform -> s_load
                #pragma unroll
                for (int oo = 0; oo < OT; ++oo) {
                    #pragma unroll
                    for (int t = 0; t < 9; ++t)
                        acc[oo] += fminf(xv[t], wp[oo * CIN * 9 + t]);
                }
            }
        }
    }

    if (active) {
        float mu = ws[0] * (1.0f / (float)NW);
        int h = h0 + ph;
        #pragma unroll
        for (int oo = 0; oo < OT; ++oo)
            out[((b * OCH + (o0 + oo)) * HH + h) * WW + pw] = mu * acc[oo];
    }
}

extern "C" void kernel_launch(void* const* d_in, const int* in_sizes, int n_in,
                              void* d_out, int out_size, void* d_ws, size_t ws_size,
                              hipStream_t stream) {
    const float* x   = (const float*)d_in[0];   // 4*32*56*56
    const float* w   = (const float*)d_in[1];   // 64*32*3*3
    float*       out = (float*)d_out;           // 4*64*56*56
    float*       ws  = (float*)d_ws;

    hipMemsetAsync(ws, 0, sizeof(float), stream);
    absmean_reduce<<<NW / (256 * 4), 256, 0, stream>>>(w, ws);
    dim3 grid(HH / TH, OCH / OT, BB);           // 14 x 16 x 4 = 896 blocks
    minconv_kernel<<<grid, 256, 0, stream>>>(x, w, ws, out);
}

// Round 2
// 96.862 us; speedup vs baseline: 1.0018x; 1.0018x over previous
//
#include <hip/hip_runtime.h>

#define CIN 32
#define OCH 64
#define HH  56
#define WW  56
#define BB  4
#define OT  4                   // output channels per block
#define TH  4                   // output rows per block
#define CG  16                  // channels staged per LDS phase
#define HALO_H (TH + 2)         // 6
#define HALO_W (WW + 2)         // 58
#define CH_STRIDE (HALO_H * HALO_W)   // 348 floats per channel
#define STAGE (CG * CH_STRIDE)        // 5568
#define NITER 22                      // ceil(5568/256)
#define STAGE_PAD (NITER * 256)       // 5632 (pad so stage loop has no tail)
#define NW 18432                      // 64*32*3*3

__global__ __launch_bounds__(256, 4) void minconv_kernel(
        const float* __restrict__ x,
        const float* __restrict__ wts,
        float* __restrict__ out) {
    __shared__ float xs[STAGE_PAD];   // 22.5 KB
    __shared__ float sred[4];

    const int tid = threadIdx.x;
    const int ht  = blockIdx.x;       // 0..13
    const int ot  = blockIdx.y;       // 0..15
    const int b   = blockIdx.z;       // 0..3
    const int h0  = ht * TH;
    const int o0  = ot * OT;

    // ---- per-block redundant mean(|w|): 72 KB from L2, once per block ----
    {
        float s = 0.f;
        for (int i = tid * 4; i < NW; i += 1024) {
            float4 v = *reinterpret_cast<const float4*>(wts + i);
            s += fabsf(v.x) + fabsf(v.y) + fabsf(v.z) + fabsf(v.w);
        }
        #pragma unroll
        for (int off = 32; off > 0; off >>= 1)
            s += __shfl_down(s, off);
        if ((tid & 63) == 0) sred[tid >> 6] = s;
        // visibility covered by the first __syncthreads below
    }

    // ---- staging address precompute (reused across both phases) ----
    int  rel[NITER];
    bool ok[NITER];
    #pragma unroll
    for (int j = 0; j < NITER; ++j) {
        int i  = tid + j * 256;
        int c  = i / CH_STRIDE;
        int r  = (i - c * CH_STRIDE) / HALO_W;
        int cc = i - c * CH_STRIDE - r * HALO_W;
        int gh = h0 - 1 + r;
        int gw = cc - 1;
        ok[j]  = (i < STAGE) & (gh >= 0) & (gh < HH) & (gw >= 0) & (gw < WW);
        rel[j] = c * (HH * WW) + gh * WW + gw;
    }

    // pixel mapping: uniform control flow; tail lanes compute a duplicate row
    const int pix = tid;
    const int pw  = pix % WW;
    int ph        = pix / WW;
    const bool active = (ph < TH);    // 224 of 256
    if (ph > TH - 1) ph = TH - 1;     // clamp -> all LDS reads in-bounds

    float acc[OT] = {0.f, 0.f, 0.f, 0.f};
    const float* wb = wts + o0 * (CIN * 9);

    for (int cg = 0; cg < CIN; cg += CG) {
        __syncthreads();              // protect previous phase's reads (+ sred)
        const float* xb = x + (b * CIN + cg) * (HH * WW);
        #pragma unroll
        for (int j = 0; j < NITER; ++j) {
            float v = 0.f;
            if (ok[j]) v = xb[rel[j]];
            xs[tid + j * 256] = v;
        }
        __syncthreads();

        const float* xp0 = xs + ph * HALO_W + pw;
        #pragma unroll 4
        for (int c = 0; c < CG; ++c) {
            const float* xp = xp0 + c * CH_STRIDE;
            float xv[9];
            #pragma unroll
            for (int kh = 0; kh < 3; ++kh)
                #pragma unroll
                for (int kw = 0; kw < 3; ++kw)
                    xv[kh * 3 + kw] = xp[kh * HALO_W + kw];
            const float* wp = wb + (cg + c) * 9;   // uniform -> s_load
            #pragma unroll
            for (int oo = 0; oo < OT; ++oo) {
                #pragma unroll
                for (int t = 0; t < 9; ++t)
                    acc[oo] += fminf(xv[t], wp[oo * (CIN * 9) + t]);
            }
        }
    }

    if (active) {
        float mu = (sred[0] + sred[1] + sred[2] + sred[3]) * (1.0f / (float)NW);
        int h = h0 + ph;
        #pragma unroll
        for (int oo = 0; oo < OT; ++oo)
            out[((b * OCH + (o0 + oo)) * HH + h) * WW + pw] = mu * acc[oo];
    }
}

extern "C" void kernel_launch(void* const* d_in, const int* in_sizes, int n_in,
                              void* d_out, int out_size, void* d_ws, size_t ws_size,
                              hipStream_t stream) {
    const float* x   = (const float*)d_in[0];   // 4*32*56*56
    const float* w   = (const float*)d_in[1];   // 64*32*3*3
    float*       out = (float*)d_out;           // 4*64*56*56

    dim3 grid(HH / TH, OCH / OT, BB);           // 14 x 16 x 4 = 896 blocks
    minconv_kernel<<<grid, 256, 0, stream>>>(x, w, out);
}

// Round 3
// 90.403 us; speedup vs baseline: 1.0734x; 1.0714x over previous
//
#include <hip/hip_runtime.h>

#define CIN  32
#define OCH  64
#define HH   56
#define WW   56
#define BB   4
#define OT   4                 // output channels per thread/block
#define IMG  (HH * WW)         // 3136
#define NW   18432             // 64*32*3*3

__global__ __launch_bounds__(256) void absmean_reduce(const float* __restrict__ w,
                                                      float* __restrict__ ws) {
    int idx = (blockIdx.x * 256 + threadIdx.x) * 4;   // 18 blocks * 256 * 4 = 18432
    float4 v = *reinterpret_cast<const float4*>(w + idx);
    float s = fabsf(v.x) + fabsf(v.y) + fabsf(v.z) + fabsf(v.w);
    #pragma unroll
    for (int off = 32; off > 0; off >>= 1)
        s += __shfl_down(s, off);
    __shared__ float smem[4];
    int lane = threadIdx.x & 63, wv = threadIdx.x >> 6;
    if (lane == 0) smem[wv] = s;
    __syncthreads();
    if (threadIdx.x == 0)
        atomicAdd(ws, smem[0] + smem[1] + smem[2] + smem[3]);
}

// block = 64 threads (1 wave) covering 64 pixels of one (b, o-tile) image.
// grid = (49 pixel-tiles, 16 o-tiles, 4 batch); b and o0 are block-uniform so
// x/w/out bases live in SGPRs; weights are wave-uniform -> s_load.
__global__ __launch_bounds__(64) void minconv_kernel(const float* __restrict__ x,
                                                     const float* __restrict__ wts,
                                                     const float* __restrict__ ws,
                                                     float* __restrict__ out) {
    const int hw = blockIdx.x * 64 + threadIdx.x;   // 0..3135, exact
    const int o0 = blockIdx.y * OT;
    const int b  = blockIdx.z;
    const int h  = hw / WW;
    const int w  = hw - h * WW;

    // 9 clamped tap offsets within a channel image + validity masks.
    int  rel[9];
    bool msk[9];
    #pragma unroll
    for (int kh = 0; kh < 3; ++kh) {
        int hh = h - 1 + kh;
        bool vh = (unsigned)hh < (unsigned)HH;
        int hc = min(max(hh, 0), HH - 1);
        #pragma unroll
        for (int kw = 0; kw < 3; ++kw) {
            int wwc = w - 1 + kw;
            bool vw = (unsigned)wwc < (unsigned)WW;
            rel[kh * 3 + kw] = hc * WW + min(max(wwc, 0), WW - 1);
            msk[kh * 3 + kw] = vh && vw;
        }
    }

    const float* xb = x + b * (CIN * IMG);          // block-uniform base (SGPR)
    const float* wb = wts + o0 * (CIN * 9);         // wave-uniform (SGPR)

    float acc[OT] = {0.f, 0.f, 0.f, 0.f};

    #pragma unroll 2
    for (int c = 0; c < CIN; ++c) {
        float xv[9];
        #pragma unroll
        for (int t = 0; t < 9; ++t) {
            float v = xb[c * IMG + rel[t]];
            xv[t] = msk[t] ? v : 0.f;               // zero-pad semantics
        }
        #pragma unroll
        for (int oo = 0; oo < OT; ++oo) {
            const float* wp = wb + oo * (CIN * 9) + c * 9;   // uniform -> s_load
            #pragma unroll
            for (int t = 0; t < 9; ++t)
                acc[oo] += fminf(xv[t], wp[t]);
        }
    }

    const float mu = ws[0] * (1.0f / (float)NW);
    float* ob = out + (b * OCH + o0) * IMG + hw;
    #pragma unroll
    for (int oo = 0; oo < OT; ++oo)
        ob[oo * IMG] = mu * acc[oo];
}

extern "C" void kernel_launch(void* const* d_in, const int* in_sizes, int n_in,
                              void* d_out, int out_size, void* d_ws, size_t ws_size,
                              hipStream_t stream) {
    const float* x   = (const float*)d_in[0];   // 4*32*56*56
    const float* w   = (const float*)d_in[1];   // 64*32*3*3
    float*       out = (float*)d_out;           // 4*64*56*56
    float*       ws  = (float*)d_ws;

    hipMemsetAsync(ws, 0, sizeof(float), stream);
    absmean_reduce<<<NW / (256 * 4), 256, 0, stream>>>(w, ws);
    dim3 grid(IMG / 64, OCH / OT, BB);          // 49 x 16 x 4 = 3136 blocks
    minconv_kernel<<<grid, 64, 0, stream>>>(x, w, ws, out);
}